// Round 3
// baseline (4214.619 us; speedup 1.0000x reference)
//
#include <hip/hip_runtime.h>

// ---------------------------------------------------------------------------
// RNN scan on MI355X — round 3.
// rnn_scan: 64 blocks x 512 threads, thread t owns column t (full k=512).
//   U column t: 192 pairs in arch VGPRs (amdgpu_waves_per_eu(2,2) pins the
//   256-reg budget so the compiler can't AGPR-ize them), 64 pairs in LDS.
//   h ping-pong in LDS (f16) -> ONE barrier per step, no partial-sum reduce.
// gemm_wx: uint4 W + b128 x-tile broadcasts (1 LDS instr : 8 dot2).
// ---------------------------------------------------------------------------

#define NRP 48            // uint4 groups (=192 pairs) per column in VGPRs
#define NTP 16            // uint4 groups (= 64 pairs) per column in LDS

typedef _Float16 h2_t __attribute__((ext_vector_type(2)));
union U32H2 { unsigned u; h2_t h; _Float16 f[2]; };

__device__ inline unsigned pkf16(float a, float b){
  U32H2 v; v.f[0] = (_Float16)a; v.f[1] = (_Float16)b; return v.u;
}

__device__ inline float dot2(unsigned a, unsigned b, float c){
  U32H2 x, y; x.u = a; y.u = b;
#if __has_builtin(__builtin_amdgcn_fdot2)
  return __builtin_amdgcn_fdot2(x.h, y.h, c, false);   // v_dot2_f32_f16
#else
  return c + (float)x.f[0]*(float)y.f[0] + (float)x.f[1]*(float)y.f[1];
#endif
}

// ---------------------------------------------------------------------------
// P: pack weights. 256 blocks x 256 threads.
//  - Wq[kp4*512 + j] (uint4): e-th element = pack(Ww[8kp4+2e][j], Ww[8kp4+2e+1][j])
//    (idx < 32*512 = 16384)
//  - U groups: item (g,t), g<64, t<512: uint4 v.e = pack(Uw[8g+2e][t], Uw[8g+2e+1][t])
//    g<NRP -> UrP[g*512+t] ; else UtP[(g-NRP)*512+t]   (idx < 64*512 = 32768)
// ---------------------------------------------------------------------------
__global__ __launch_bounds__(256) void prep_pack(const float* __restrict__ Ww,
                                                 const float* __restrict__ Uw,
                                                 uint4* __restrict__ Wq,
                                                 uint4* __restrict__ UrP,
                                                 uint4* __restrict__ UtP){
  int idx = blockIdx.x*256 + threadIdx.x;
  if (idx < 32*512){ // W pack
    int kp4 = idx >> 9, j = idx & 511;
    uint4 v; unsigned* vv = (unsigned*)&v;
    #pragma unroll
    for (int e=0;e<4;e++)
      vv[e] = pkf16(Ww[(8*kp4+2*e)*512 + j], Ww[(8*kp4+2*e+1)*512 + j]);
    Wq[idx] = v;
  }
  if (idx < 64*512){ // U pack
    int g = idx >> 9, t = idx & 511;
    uint4 v; unsigned* vv = (unsigned*)&v;
    #pragma unroll
    for (int e=0;e<4;e++)
      vv[e] = pkf16(Uw[(8*g+2*e)*512 + t], Uw[(8*g+2*e+1)*512 + t]);
    if (g < NRP) UrP[g*512 + t] = v;
    else         UtP[(g-NRP)*512 + t] = v;
  }
}

// ---------------------------------------------------------------------------
// G: wx GEMM. Block = 32 seq rows x 512 cols; thread owns cols (tid, tid+256).
// Output wxp[(b*2048+s)*256 + j] = pack(col j, col j+256). 4096 blocks.
// ---------------------------------------------------------------------------
__global__ __launch_bounds__(256) void gemm_wx(const float* __restrict__ x,
                                               const uint4* __restrict__ Wq,
                                               const float* __restrict__ Wb,
                                               unsigned* __restrict__ wxp){
  __shared__ __align__(16) unsigned xt[32][128];   // 16 KB, 4*kp4-aligned
  const int tid = threadIdx.x;
  const int b = blockIdx.x >> 6, sb = blockIdx.x & 63;
  const float* xrow = x + ((size_t)(b*2048 + sb*32))*256;
  #pragma unroll
  for (int i=0;i<8;i++){
    int f = i*256 + tid;
    int r = f >> 6, c4 = f & 63;
    float4 v = ((const float4*)xrow)[r*64 + c4];
    xt[r][2*c4]   = pkf16(v.x, v.y);
    xt[r][2*c4+1] = pkf16(v.z, v.w);
  }
  float acc0[32], acc1[32];
  #pragma unroll
  for (int r=0;r<32;r++){ acc0[r]=0.f; acc1[r]=0.f; }
  __syncthreads();
  #pragma unroll 2
  for (int kp4=0;kp4<32;kp4++){
    uint4 w0 = Wq[kp4*512 + tid];
    uint4 w1 = Wq[kp4*512 + tid + 256];
    #pragma unroll
    for (int r=0;r<32;r++){
      uint4 xv = *(const uint4*)&xt[r][4*kp4];     // b128 broadcast
      acc0[r] = dot2(w0.w, xv.w, dot2(w0.z, xv.z, dot2(w0.y, xv.y, dot2(w0.x, xv.x, acc0[r]))));
      acc1[r] = dot2(w1.w, xv.w, dot2(w1.z, xv.z, dot2(w1.y, xv.y, dot2(w1.x, xv.x, acc1[r]))));
    }
  }
  float wb0 = Wb[tid], wb1 = Wb[tid+256];
  unsigned* o = wxp + ((size_t)(b*2048 + sb*32))*256;
  #pragma unroll
  for (int r=0;r<32;r++)
    o[r*256 + tid] = pkf16(acc0[r]+wb0, acc1[r]+wb1);
}

// ---------------------------------------------------------------------------
// R: sequential scan. 64 blocks x 512 threads, exactly 2 waves/EU.
// LDS: utail 128 KB + h ping-pong 2 KB + rbuf -> ~130 KB.
// ---------------------------------------------------------------------------
__global__ __launch_bounds__(512)
__attribute__((amdgpu_waves_per_eu(2,2)))
void rnn_scan(const uint4* __restrict__ UrP,
              const uint4* __restrict__ UtP,
              const unsigned* __restrict__ wxp,
              const float* __restrict__ Ub,
              const float* __restrict__ Vw,
              const float* __restrict__ Vb,
              float* __restrict__ out){
  __shared__ __align__(16) _Float16 hbuf[2][512];  // ping-pong h
  __shared__ uint4 utail[NTP*512];                 // 128 KB
  __shared__ float rbuf[16];
  const int t = threadIdx.x;
  const int b = blockIdx.x;

  uint4 ureg[NRP];                                 // 192 arch VGPRs
  #pragma unroll
  for (int j=0;j<NRP;j++) ureg[j] = UrP[j*512 + t];
  #pragma unroll
  for (int i=0;i<NTP;i++) utail[i*512 + t] = UtP[i*512 + t];
  hbuf[0][t] = (_Float16)0.f;                      // h0 = 0
  const float ub_c = Ub[t];
  const unsigned* wxb = wxp + (size_t)b*2048*256;
  const int wxo = t & 255;
  const int hi  = t >> 8;                          // wave-uniform
  unsigned wc = wxb[wxo];                          // wx[0]
  unsigned wn = wxb[256 + wxo];                    // wx[1]
  __syncthreads();

  float hf = 0.f;
  #pragma unroll 1
  for (int ts=0; ts<2048; ts++){
    const uint4* hq = (const uint4*)hbuf[ts & 1];  // pairs, broadcast reads
    U32H2 wv; wv.u = wc;
    wc = wn;
    int tn = (ts+2 < 2048) ? (ts+2) : 2047;
    wn = wxb[tn*256 + wxo];                        // prefetch wx[ts+2]

    float a0 = (float)wv.f[hi] + ub_c;             // seed with wx + Ub
    float a1 = 0.f, a2 = 0.f, a3 = 0.f;
    #pragma unroll
    for (int j=0;j<NRP;j+=2){                      // pairs 0..191 from VGPRs
      uint4 h0 = hq[j], h1 = hq[j+1];
      uint4 u0 = ureg[j], u1 = ureg[j+1];
      a0 = dot2(u0.x, h0.x, a0); a1 = dot2(u0.y, h0.y, a1);
      a2 = dot2(u0.z, h0.z, a2); a3 = dot2(u0.w, h0.w, a3);
      a0 = dot2(u1.x, h1.x, a0); a1 = dot2(u1.y, h1.y, a1);
      a2 = dot2(u1.z, h1.z, a2); a3 = dot2(u1.w, h1.w, a3);
    }
    #pragma unroll
    for (int i=0;i<NTP;i+=2){                      // pairs 192..255 from LDS
      uint4 h0 = hq[NRP+i], h1 = hq[NRP+i+1];
      uint4 u0 = utail[i*512+t], u1 = utail[(i+1)*512+t];
      a0 = dot2(u0.x, h0.x, a0); a1 = dot2(u0.y, h0.y, a1);
      a2 = dot2(u0.z, h0.z, a2); a3 = dot2(u0.w, h0.w, a3);
      a0 = dot2(u1.x, h1.x, a0); a1 = dot2(u1.y, h1.y, a1);
      a2 = dot2(u1.z, h1.z, a2); a3 = dot2(u1.w, h1.w, a3);
    }
    float pre = (a0+a1) + (a2+a3);
    hf = 1.f - 2.f/(__expf(2.f*pre) + 1.f);        // tanh, saturates cleanly
    hbuf[(ts+1) & 1][t] = (_Float16)hf;
    __syncthreads();                               // single barrier per step
  }

  // epilogue: out[b,:] = sigmoid(h_T @ V + Vb); thread t holds h_T[t]
  float p0 = hf*Vw[2*t], p1 = hf*Vw[2*t+1];
  #pragma unroll
  for (int off=32; off>0; off>>=1){
    p0 += __shfl_down(p0, off);
    p1 += __shfl_down(p1, off);
  }
  if ((t & 63) == 0){
    rbuf[(t>>6)*2]   = p0;
    rbuf[(t>>6)*2+1] = p1;
  }
  __syncthreads();
  if (t == 0){
    float s0 = Vb[0], s1 = Vb[1];
    #pragma unroll
    for (int w=0;w<8;w++){ s0 += rbuf[2*w]; s1 += rbuf[2*w+1]; }
    out[2*b]   = 1.f/(1.f + __expf(-s0));
    out[2*b+1] = 1.f/(1.f + __expf(-s1));
  }
}

// ---------------------------------------------------------------------------
extern "C" void kernel_launch(void* const* d_in, const int* in_sizes, int n_in,
                              void* d_out, int out_size, void* d_ws, size_t ws_size,
                              hipStream_t stream) {
  const float* x  = (const float*)d_in[0];   // [64,2048,256]
  const float* Ww = (const float*)d_in[1];   // [256,512]
  const float* Wb = (const float*)d_in[2];   // [512]
  const float* Uw = (const float*)d_in[3];   // [512,512]
  const float* Ub = (const float*)d_in[4];   // [512]
  const float* Vw = (const float*)d_in[5];   // [512,2]
  const float* Vb = (const float*)d_in[6];   // [2]
  float* out = (float*)d_out;                // [64,2]

  char* ws = (char*)d_ws;
  unsigned* wxp = (unsigned*)ws;                             // 134,217,728 B
  uint4*    Wq  = (uint4*)(ws + 134217728);                  //     262,144 B
  uint4*    UrP = (uint4*)(ws + 134217728 + 262144);         //     393,216 B
  uint4*    UtP = (uint4*)(ws + 134217728 + 262144 + 393216);//     131,072 B

  prep_pack<<<256, 256, 0, stream>>>(Ww, Uw, Wq, UrP, UtP);
  gemm_wx  <<<4096, 256, 0, stream>>>(x, Wq, Wb, wxp);
  rnn_scan <<<64, 512, 0, stream>>>(UrP, UtP, wxp, Ub, Vw, Vb, out);
}

// Round 4
// 3177.743 us; speedup vs baseline: 1.3263x; 1.3263x over previous
//
#include <hip/hip_runtime.h>

// ---------------------------------------------------------------------------
// RNN scan on MI355X — round 4.
// Register-file reality (R2/R3 evidence): at 2 waves/EU the unified V+A file
// is 256 regs/wave (128 arch VGPR + 128 AGPR). U needs 256 u32/thread -> the
// whole file. Split: 52 quads (208 u32) in regs (~80 V + 128 A w/ moves),
// 12 quads (48 u32) in LDS. k-quarter per wave keeps h reads broadcast.
// ---------------------------------------------------------------------------

#define NRP 52            // U quads per thread in registers (V+A)
#define NTP 12            // U quads per thread in LDS

typedef _Float16 h2_t __attribute__((ext_vector_type(2)));
union U32H2 { unsigned u; h2_t h; _Float16 f[2]; };

__device__ inline unsigned pkf16(float a, float b){
  U32H2 v; v.f[0] = (_Float16)a; v.f[1] = (_Float16)b; return v.u;
}

__device__ inline float dot2(unsigned a, unsigned b, float c){
  U32H2 x, y; x.u = a; y.u = b;
#if __has_builtin(__builtin_amdgcn_fdot2)
  return __builtin_amdgcn_fdot2(x.h, y.h, c, false);   // v_dot2_f32_f16
#else
  return c + (float)x.f[0]*(float)y.f[0] + (float)x.f[1]*(float)y.f[1];
#endif
}

// ---------------------------------------------------------------------------
// P: pack weights. 256 blocks x 256 threads.
//  - Wq[kp4*512 + j] (uint4): e-th elem = pack(Ww[8kp4+2e][j], Ww[8kp4+2e+1][j])
//  - U quads for the scan: thread t (t<512): kq=t>>7, cp=t&127,
//    quad j (j<64): pair p = 64*kq + j, element e: cols c_e = cp + 128e
//      v.e = pack(Uw[2p][c_e], Uw[2p+1][c_e])
//    j < NRP -> UrP[j*512 + t] ; else UtP[(j-NRP)*512 + t]
// ---------------------------------------------------------------------------
__global__ __launch_bounds__(256) void prep_pack(const float* __restrict__ Ww,
                                                 const float* __restrict__ Uw,
                                                 uint4* __restrict__ Wq,
                                                 uint4* __restrict__ UrP,
                                                 uint4* __restrict__ UtP){
  int idx = blockIdx.x*256 + threadIdx.x;
  if (idx < 32*512){ // W pack
    int kp4 = idx >> 9, j = idx & 511;
    uint4 v; unsigned* vv = (unsigned*)&v;
    #pragma unroll
    for (int e=0;e<4;e++)
      vv[e] = pkf16(Ww[(8*kp4+2*e)*512 + j], Ww[(8*kp4+2*e+1)*512 + j]);
    Wq[idx] = v;
  }
  if (idx < 64*512){ // U pack
    int j = idx >> 9, t = idx & 511;
    int kq = t >> 7, cp = t & 127;
    int p = 64*kq + j, k0 = 2*p;
    uint4 v; unsigned* vv = (unsigned*)&v;
    #pragma unroll
    for (int e=0;e<4;e++){
      int c = cp + 128*e;
      vv[e] = pkf16(Uw[k0*512 + c], Uw[(k0+1)*512 + c]);
    }
    if (j < NRP) UrP[j*512 + t] = v;
    else         UtP[(j-NRP)*512 + t] = v;
  }
}

// ---------------------------------------------------------------------------
// G: wx GEMM (unchanged from R3). Block = 32 seq rows x 512 cols.
// Output wxp[(b*2048+s)*256 + j] = pack(col j, col j+256). 4096 blocks.
// ---------------------------------------------------------------------------
__global__ __launch_bounds__(256) void gemm_wx(const float* __restrict__ x,
                                               const uint4* __restrict__ Wq,
                                               const float* __restrict__ Wb,
                                               unsigned* __restrict__ wxp){
  __shared__ __align__(16) unsigned xt[32][128];   // 16 KB
  const int tid = threadIdx.x;
  const int b = blockIdx.x >> 6, sb = blockIdx.x & 63;
  const float* xrow = x + ((size_t)(b*2048 + sb*32))*256;
  #pragma unroll
  for (int i=0;i<8;i++){
    int f = i*256 + tid;
    int r = f >> 6, c4 = f & 63;
    float4 v = ((const float4*)xrow)[r*64 + c4];
    xt[r][2*c4]   = pkf16(v.x, v.y);
    xt[r][2*c4+1] = pkf16(v.z, v.w);
  }
  float acc0[32], acc1[32];
  #pragma unroll
  for (int r=0;r<32;r++){ acc0[r]=0.f; acc1[r]=0.f; }
  __syncthreads();
  #pragma unroll 2
  for (int kp4=0;kp4<32;kp4++){
    uint4 w0 = Wq[kp4*512 + tid];
    uint4 w1 = Wq[kp4*512 + tid + 256];
    #pragma unroll
    for (int r=0;r<32;r++){
      uint4 xv = *(const uint4*)&xt[r][4*kp4];     // b128 broadcast
      acc0[r] = dot2(w0.w, xv.w, dot2(w0.z, xv.z, dot2(w0.y, xv.y, dot2(w0.x, xv.x, acc0[r]))));
      acc1[r] = dot2(w1.w, xv.w, dot2(w1.z, xv.z, dot2(w1.y, xv.y, dot2(w1.x, xv.x, acc1[r]))));
    }
  }
  float wb0 = Wb[tid], wb1 = Wb[tid+256];
  unsigned* o = wxp + ((size_t)(b*2048 + sb*32))*256;
  #pragma unroll
  for (int r=0;r<32;r++)
    o[r*256 + tid] = pkf16(acc0[r]+wb0, acc1[r]+wb1);
}

// ---------------------------------------------------------------------------
// R: sequential scan. 64 blocks x 512 threads, 2 waves/EU.
// Thread t: kq=t>>7, cp=t&127, cols {cp, cp+128, cp+256, cp+384}, 64 pairs.
// LDS: utail 96 KB + h 1 KB + ptab 8 KB ≈ 105.3 KB.
// ---------------------------------------------------------------------------
__global__ __launch_bounds__(512)
__attribute__((amdgpu_waves_per_eu(2,2)))
void rnn_scan(const uint4* __restrict__ UrP,
              const uint4* __restrict__ UtP,
              const unsigned* __restrict__ wxp,
              const float* __restrict__ Ub,
              const float* __restrict__ Vw,
              const float* __restrict__ Vb,
              float* __restrict__ out){
  __shared__ __align__(16) _Float16 harr[512];
  __shared__ uint4 utail[NTP*512];                 // 96 KB
  __shared__ float ptab[4*512];                    // partials [kq][col]
  __shared__ float rbuf[16];
  const int t  = threadIdx.x;
  const int b  = blockIdx.x;
  const int kq = t >> 7;

  uint4 ureg[NRP];                                 // 208 u32 (V+A mix)
  #pragma unroll
  for (int j=0;j<NRP;j++) ureg[j] = UrP[j*512 + t];
  #pragma unroll
  for (int i=0;i<NTP;i++) utail[i*512 + t] = UtP[i*512 + t];
  harr[t] = (_Float16)0.f;                         // h0 = 0
  const float ub_c = Ub[t];
  const unsigned* wxb = wxp + (size_t)b*2048*256;
  const int wxo = t & 255;
  const int hi  = t >> 8;                          // wx pack element
  unsigned wc = wxb[wxo];                          // wx[0]
  unsigned wn = wxb[256 + wxo];                    // wx[1]
  __syncthreads();

  // broadcast h slice for this wave's k-quarter: quads [16kq, 16kq+16)
  const uint4* hq = ((const uint4*)harr) + 16*kq;
  float hf = 0.f;

  #pragma unroll 1
  for (int ts=0; ts<2048; ts++){
    unsigned wuse = wc;
    wc = wn;
    int tn = (ts+2 < 2048) ? (ts+2) : 2047;
    wn = wxb[tn*256 + wxo];                        // prefetch wx[ts+2]

    float a0=0.f, a1=0.f, a2=0.f, a3=0.f;          // 4 columns
    #pragma unroll
    for (int g=0; g<NRP/4; g++){                   // register-resident quads
      uint4 hv = hq[g];                            // pairs 4g..4g+3 (bcast)
      uint4 u0 = ureg[4*g+0], u1 = ureg[4*g+1];
      uint4 u2 = ureg[4*g+2], u3 = ureg[4*g+3];
      a0 = dot2(u0.x, hv.x, a0); a1 = dot2(u0.y, hv.x, a1);
      a2 = dot2(u0.z, hv.x, a2); a3 = dot2(u0.w, hv.x, a3);
      a0 = dot2(u1.x, hv.y, a0); a1 = dot2(u1.y, hv.y, a1);
      a2 = dot2(u1.z, hv.y, a2); a3 = dot2(u1.w, hv.y, a3);
      a0 = dot2(u2.x, hv.z, a0); a1 = dot2(u2.y, hv.z, a1);
      a2 = dot2(u2.z, hv.z, a2); a3 = dot2(u2.w, hv.z, a3);
      a0 = dot2(u3.x, hv.w, a0); a1 = dot2(u3.y, hv.w, a1);
      a2 = dot2(u3.z, hv.w, a2); a3 = dot2(u3.w, hv.w, a3);
    }
    #pragma unroll
    for (int g=0; g<NTP/4; g++){                   // LDS-resident quads
      uint4 hv = hq[NRP/4 + g];
      uint4 u0 = utail[(4*g+0)*512+t], u1 = utail[(4*g+1)*512+t];
      uint4 u2 = utail[(4*g+2)*512+t], u3 = utail[(4*g+3)*512+t];
      a0 = dot2(u0.x, hv.x, a0); a1 = dot2(u0.y, hv.x, a1);
      a2 = dot2(u0.z, hv.x, a2); a3 = dot2(u0.w, hv.x, a3);
      a0 = dot2(u1.x, hv.y, a0); a1 = dot2(u1.y, hv.y, a1);
      a2 = dot2(u1.z, hv.y, a2); a3 = dot2(u1.w, hv.y, a3);
      a0 = dot2(u2.x, hv.z, a0); a1 = dot2(u2.y, hv.z, a1);
      a2 = dot2(u2.z, hv.z, a2); a3 = dot2(u2.w, hv.z, a3);
      a0 = dot2(u3.x, hv.w, a0); a1 = dot2(u3.y, hv.w, a1);
      a2 = dot2(u3.z, hv.w, a2); a3 = dot2(u3.w, hv.w, a3);
    }
    // partials: ptab[kq][col]; per-wave stride-1 -> conflict-free
    {
      int cp = t & 127;
      ptab[kq*512 + cp      ] = a0;
      ptab[kq*512 + cp + 128] = a1;
      ptab[kq*512 + cp + 256] = a2;
      ptab[kq*512 + cp + 384] = a3;
    }
    __syncthreads();                               // ptab ready; h reads done
    // reduce: thread t owns column t
    {
      float s = (ptab[t] + ptab[512+t]) + (ptab[1024+t] + ptab[1536+t]);
      U32H2 wv; wv.u = wuse;
      float pre = s + (float)wv.f[hi] + ub_c;
      hf = 1.f - 2.f/(__expf(2.f*pre) + 1.f);      // tanh, saturates cleanly
      harr[t] = (_Float16)hf;
    }
    __syncthreads();                               // h visible for next step
  }

  // epilogue: out[b,:] = sigmoid(h_T @ V + Vb); thread t holds h_T[t]
  float p0 = hf*Vw[2*t], p1 = hf*Vw[2*t+1];
  #pragma unroll
  for (int off=32; off>0; off>>=1){
    p0 += __shfl_down(p0, off);
    p1 += __shfl_down(p1, off);
  }
  if ((t & 63) == 0){
    rbuf[(t>>6)*2]   = p0;
    rbuf[(t>>6)*2+1] = p1;
  }
  __syncthreads();
  if (t == 0){
    float s0 = Vb[0], s1 = Vb[1];
    #pragma unroll
    for (int w=0;w<8;w++){ s0 += rbuf[2*w]; s1 += rbuf[2*w+1]; }
    out[2*b]   = 1.f/(1.f + __expf(-s0));
    out[2*b+1] = 1.f/(1.f + __expf(-s1));
  }
}

// ---------------------------------------------------------------------------
extern "C" void kernel_launch(void* const* d_in, const int* in_sizes, int n_in,
                              void* d_out, int out_size, void* d_ws, size_t ws_size,
                              hipStream_t stream) {
  const float* x  = (const float*)d_in[0];   // [64,2048,256]
  const float* Ww = (const float*)d_in[1];   // [256,512]
  const float* Wb = (const float*)d_in[2];   // [512]
  const float* Uw = (const float*)d_in[3];   // [512,512]
  const float* Ub = (const float*)d_in[4];   // [512]
  const float* Vw = (const float*)d_in[5];   // [512,2]
  const float* Vb = (const float*)d_in[6];   // [2]
  float* out = (float*)d_out;                // [64,2]

  char* ws = (char*)d_ws;
  unsigned* wxp = (unsigned*)ws;                              // 134,217,728 B
  uint4*    Wq  = (uint4*)(ws + 134217728);                   //     262,144 B
  uint4*    UrP = (uint4*)(ws + 134217728 + 262144);          // NRP*512*16 B
  uint4*    UtP = (uint4*)(ws + 134217728 + 262144 + (size_t)NRP*512*16);

  prep_pack<<<256, 256, 0, stream>>>(Ww, Uw, Wq, UrP, UtP);
  gemm_wx  <<<4096, 256, 0, stream>>>(x, Wq, Wb, wxp);
  rnn_scan <<<64, 512, 0, stream>>>(UrP, UtP, wxp, Ub, Vw, Vb, out);
}